// Round 10
// baseline (250.964 us; speedup 1.0000x reference)
//
#include <hip/hip_runtime.h>
#include <hip/hip_bf16.h>

// SelfAttentionMasked: B=4, N=2048, DIM=1024, H=16, DH=64
// cvt(x) -> transpose_cvt(W) -> packmask -> QKV GEMM (gload_lds+swizzle, LDS-restaged
// coalesced epilogue, Q pre-scaled by 0.125*log2e) -> flash attn (32x32x16 swapped
// QK^T, in-register P via permlane32_swap, key-half pipeline, rolled kt loop)
// -> out GEMM + bias

typedef __attribute__((ext_vector_type(8))) short bf16x8;
typedef __attribute__((ext_vector_type(4))) float f32x4;
typedef __attribute__((ext_vector_type(16))) float f32x16;
typedef __attribute__((ext_vector_type(2))) unsigned int uint2v;

__device__ __forceinline__ unsigned short f2bf(float f) {
  unsigned u = __builtin_bit_cast(unsigned, f);
  u += 0x7fffu + ((u >> 16) & 1u);   // RNE
  return (unsigned short)(u >> 16);
}

// async global->LDS, 16B per lane; LDS dest linear (wave-uniform base + lane*16)
__device__ __forceinline__ void gload16(const void* g, void* l) {
  __builtin_amdgcn_global_load_lds(
      (const __attribute__((address_space(1))) unsigned int*)g,
      (__attribute__((address_space(3))) unsigned int*)l, 16, 0, 0);
}

// swizzled b128 read from a [rows][64-elem] linear LDS tile staged with
// source-byte ^= ((row&7)<<4). elem must be a multiple of 8.
__device__ __forceinline__ bf16x8 ldsw(const short* base, int row, int elem) {
  const char* p = (const char*)base + row * 128 + ((elem * 2) ^ ((row & 7) << 4));
  return *(const bf16x8*)p;
}

// ---------------- convert f32 -> bf16 flat ----------------
__global__ __launch_bounds__(256) void k_cvt(const float* __restrict__ in,
                                             unsigned short* __restrict__ out) {
  int i = (blockIdx.x * 256 + threadIdx.x) * 4;
  float4 v = *reinterpret_cast<const float4*>(in + i);
  ushort4 o;
  o.x = f2bf(v.x); o.y = f2bf(v.y); o.z = f2bf(v.z); o.w = f2bf(v.w);
  *reinterpret_cast<ushort4*>(out + i) = o;
}

// ------- transpose + convert: in [rows][cols] f32 -> out [cols][rows] bf16 -------
__global__ __launch_bounds__(256) void k_transpose_cvt(const float* __restrict__ in,
                                                       unsigned short* __restrict__ out,
                                                       int rows, int cols) {
  __shared__ float tile[32][33];
  int tx = threadIdx.x & 31, ty = threadIdx.x >> 5;  // 32 x 8
  int c0 = blockIdx.x * 32, r0 = blockIdx.y * 32;
#pragma unroll
  for (int i = 0; i < 32; i += 8)
    tile[ty + i][tx] = in[(size_t)(r0 + ty + i) * cols + (c0 + tx)];
  __syncthreads();
#pragma unroll
  for (int i = 0; i < 32; i += 8)
    out[(size_t)(c0 + ty + i) * rows + (r0 + tx)] = f2bf(tile[tx][ty + i]);
}

// ------- pack mask int32 [row][2048] -> bits uint64 [row][32] (bit k = masked) ----
__global__ __launch_bounds__(256) void k_packmask(const int* __restrict__ mask,
                                                  unsigned long long* __restrict__ pack) {
  const int row = blockIdx.x;              // b*2048 + n
  const int t = threadIdx.x, w = t >> 6, lane = t & 63;
  const int* mrow = mask + (size_t)row * 2048;
#pragma unroll
  for (int it = 0; it < 8; ++it) {
    int key = it * 256 + w * 64 + lane;
    unsigned long long bal = __ballot(mrow[key] == 1);
    if (lane == 0) pack[(size_t)row * 32 + it * 4 + w] = bal;
  }
}

// ---------------- GEMM: C[8192][N] = A[8192][1024] @ Bt[N][1024]^T ----------------
// EPI==0: LDS-restaged coalesced epilogue into Q (pre-scaled) / K [bh][2048][64],
//         V^T [bh][64][2048]. grid (24,64).  EPI==1: f32 out + bias. grid (8,64).
// Default block order (no XCD swizzle: R9 showed default round-robin gives each XCD
// only 3 of 24 B-panels = better L2 reuse than chunked).
template <int EPI>
__global__ __launch_bounds__(256) void k_gemm(
    const unsigned short* __restrict__ A, const unsigned short* __restrict__ Bt,
    unsigned short* __restrict__ Qo, unsigned short* __restrict__ Ko,
    unsigned short* __restrict__ Vo, float* __restrict__ Co,
    const float* __restrict__ bias) {
  // k-loop: As = Smem[0:8192), Bs = Smem[8192:16384). epilogue: Cs = Smem, stride 132.
  __shared__ __align__(16) short Smem[16896];   // 33792 B
  short* As = Smem;
  short* Bs = Smem + 8192;
  const int t = threadIdx.x;
  const int bn = blockIdx.x, bm = blockIdx.y;
  const int wid = t >> 6, lane = t & 63, g = lane >> 4, l15 = lane & 15;
  const int wr = wid >> 1, wc = wid & 1;
  f32x4 zero = {0.f, 0.f, 0.f, 0.f};
  f32x4 acc[4][4];
#pragma unroll
  for (int i = 0; i < 4; ++i)
#pragma unroll
    for (int j = 0; j < 4; ++j) acc[i][j] = zero;

  const char* Ab = (const char*)(A + (size_t)bm * 128 * 1024);  // row stride 2048B
  const char* Bb = (const char*)(Bt + (size_t)bn * 128 * 1024);

  for (int k0 = 0; k0 < 2048; k0 += 128) {   // K-step: 64 elems = 128 bytes
#pragma unroll
    for (int q = 0; q < 4; ++q) {
      int idx = t + q * 256, r = idx >> 3, c = idx & 7;
      int sw = (c * 16) ^ ((r & 7) << 4);
      gload16(Ab + (size_t)r * 2048 + k0 + sw, (char*)As + idx * 16);
      gload16(Bb + (size_t)r * 2048 + k0 + sw, (char*)Bs + idx * 16);
    }
    asm volatile("s_waitcnt vmcnt(0)" ::: "memory");
    __syncthreads();
#pragma unroll
    for (int ks = 0; ks < 2; ++ks) {
      bf16x8 a[4], b[4];
#pragma unroll
      for (int mi = 0; mi < 4; ++mi) a[mi] = ldsw(As, wr * 64 + mi * 16 + l15, ks * 32 + g * 8);
#pragma unroll
      for (int ni = 0; ni < 4; ++ni) b[ni] = ldsw(Bs, wc * 64 + ni * 16 + l15, ks * 32 + g * 8);
#pragma unroll
      for (int mi = 0; mi < 4; ++mi)
#pragma unroll
        for (int ni = 0; ni < 4; ++ni)
          acc[mi][ni] = __builtin_amdgcn_mfma_f32_16x16x32_bf16(a[mi], b[ni], acc[mi][ni], 0, 0, 0);
    }
    __syncthreads();   // also guards Smem reuse by the epilogue
  }

  if (EPI == 1) {
#pragma unroll
    for (int mi = 0; mi < 4; ++mi)
#pragma unroll
      for (int ni = 0; ni < 4; ++ni)
#pragma unroll
        for (int j = 0; j < 4; ++j) {
          int row = bm * 128 + wr * 64 + mi * 16 + g * 4 + j;
          int col = bn * 128 + wc * 64 + ni * 16 + l15;
          Co[(size_t)row * 1024 + col] = acc[mi][ni][j] + bias[col];
        }
    return;
  }

  // ---- EPI==0 coalesced epilogue ----
  const int s = bn >> 3;                 // 0=Q,1=K,2=V (uniform per block)
  const int h0 = (bn & 7) * 2;           // two heads in this tile
  const int bglob = (bm * 128) >> 11;    // batch (tile never straddles batches)
  const int n0 = (bm * 128) & 2047;

  if (s < 2) {
    const float qs = (s == 0) ? 0.18033688011112042f : 1.0f;  // 0.125*log2(e) for Q
    // stage Cs[row][col], stride 132 shorts
#pragma unroll
    for (int mi = 0; mi < 4; ++mi)
#pragma unroll
      for (int ni = 0; ni < 4; ++ni)
#pragma unroll
        for (int j = 0; j < 4; ++j)
          Smem[(wr * 64 + mi * 16 + g * 4 + j) * 132 + wc * 64 + ni * 16 + l15] =
              (short)f2bf(acc[mi][ni][j] * qs);
    __syncthreads();
    // copy out: thread -> row r, head-half hh; 64 shorts = 128B contiguous dest
    int r = t >> 1, hh = t & 1;
    unsigned short* dst = (s == 0 ? Qo : Ko) +
        (((size_t)(bglob * 16 + h0 + hh)) * 2048 + n0 + r) * 64;
    const short* src = Smem + r * 132 + hh * 64;
#pragma unroll
    for (int k = 0; k < 8; ++k) {
      uint2 a = *reinterpret_cast<const uint2*>(src + k * 8);
      uint2 b2 = *reinterpret_cast<const uint2*>(src + k * 8 + 4);
      uint4 w = {a.x, a.y, b2.x, b2.y};
      *reinterpret_cast<uint4*>(dst + k * 8) = w;
    }
  } else {
    // V: stage TRANSPOSED Cs_t[col][row] stride 132; per-fragment 4 j-rows adjacent -> b64
#pragma unroll
    for (int mi = 0; mi < 4; ++mi)
#pragma unroll
      for (int ni = 0; ni < 4; ++ni) {
        unsigned x0 = f2bf(acc[mi][ni][0]), x1 = f2bf(acc[mi][ni][1]);
        unsigned x2 = f2bf(acc[mi][ni][2]), x3 = f2bf(acc[mi][ni][3]);
        uint2 pk = {x0 | (x1 << 16), x2 | (x3 << 16)};
        int col = wc * 64 + ni * 16 + l15;
        int row = wr * 64 + mi * 16 + g * 4;
        *reinterpret_cast<uint2*>(Smem + col * 132 + row) = pk;
      }
    __syncthreads();
    // copy out: thread -> col c (head h, dim d), row-half seg; 64 shorts contiguous dest
    int c = t >> 1, seg = t & 1;
    int h = h0 + (c >> 6), d = c & 63;
    unsigned short* dst = Vo + ((size_t)(bglob * 16 + h) * 64 + d) * 2048 + n0 + seg * 64;
    const short* src = Smem + c * 132 + seg * 64;
#pragma unroll
    for (int k = 0; k < 8; ++k) {
      uint2 a = *reinterpret_cast<const uint2*>(src + k * 8);
      uint2 b2 = *reinterpret_cast<const uint2*>(src + k * 8 + 4);
      uint4 w = {a.x, a.y, b2.x, b2.y};
      *reinterpret_cast<uint4*>(dst + k * 8) = w;
    }
  }
}

// ---------------- flash attention (32x32x16) ----------------
// grid 1024 (XCD-swizzled), 256 threads = 4 waves x 32 q-rows (QBLK=128); KV tile 64.
// Swapped QK^T (32x32x16): S^T = mfma(K, Q) -> D col=lane&31=q (lane-local q!),
// row = (reg&3)+8*(reg>>2)+4*hi = key. P redistribution to PV A-fragments is done
// IN REGISTER: 8 bf16-pair packs + 4 permlane32_swap per 32-key block (no P LDS,
// no lgkmcnt serialization). LDS = 32KB (K/V dbuf only). Rolled kt loop, runtime cb.
__global__ __launch_bounds__(256) void k_attn(
    const unsigned short* __restrict__ Q, const unsigned short* __restrict__ K,
    const unsigned short* __restrict__ Vt_g, const unsigned long long* __restrict__ pack,
    unsigned short* __restrict__ O) {
  __shared__ __align__(16) short Ks[2][64 * 64];    // 16KB [key][d]
  __shared__ __align__(16) short Vt[2][64 * 64];    // 16KB [dout][key]
  const int bid0 = blockIdx.x;
  const int bid = (bid0 & 7) * 128 + (bid0 >> 3);   // XCD chunked swizzle (1024%8==0)
  const int qt = bid & 15, bh = bid >> 4;           // 16 q-tiles of 128
  const int b = bh >> 4;
  const int t = threadIdx.x, wid = t >> 6, lane = t & 63;
  const int l31 = lane & 31, hi = lane >> 5;
  const char* Kb = (const char*)(K + (size_t)bh * (2048 * 64));     // tile stride 8192B
  const char* Vb = (const char*)(Vt_g + (size_t)bh * (64 * 2048));  // row stride 4096B
  const unsigned short* Qb = Q + (size_t)bh * (2048 * 64);

  // staging offsets: 2x 16B gloads per array per thread (8KB tile / 256 thr)
  const int i0 = t, i1 = t + 256;
  const int r0s = i0 >> 3, r1s = i1 >> 3, cs = (t & 7) * 16;
  const int k0off = r0s * 128 + (cs ^ ((r0s & 7) << 4));
  const int k1off = r1s * 128 + (cs ^ ((r1s & 7) << 4));
  const int v0off = r0s * 4096 + (cs ^ ((r0s & 7) << 4));
  const int v1off = r1s * 4096 + (cs ^ ((r1s & 7) << 4));

  // prologue: stage K/V tile 0
  gload16(Kb + k0off, (char*)&Ks[0][0] + i0 * 16);
  gload16(Kb + k1off, (char*)&Ks[0][0] + i1 * 16);
  gload16(Vb + v0off, (char*)&Vt[0][0] + i0 * 16);
  gload16(Vb + v1off, (char*)&Vt[0][0] + i1 * 16);

  // Q fragments (B-operand): lane supplies Q[q=l31][d = c*16 + hi*8 + e]
  const int qrow = qt * 128 + wid * 32 + l31;
  bf16x8 qf[4];
#pragma unroll
  for (int c = 0; c < 4; ++c)
    qf[c] = *reinterpret_cast<const bf16x8*>(Qb + (size_t)qrow * 64 + c * 16 + hi * 8);
  const unsigned long long* mrow = pack + ((size_t)b * 2048 + qrow) * 32;
  asm volatile("s_waitcnt vmcnt(0)" ::: "memory");
  __syncthreads();

  f32x16 oacc0 = {0.f,0.f,0.f,0.f,0.f,0.f,0.f,0.f,0.f,0.f,0.f,0.f,0.f,0.f,0.f,0.f};
  f32x16 oacc1 = {0.f,0.f,0.f,0.f,0.f,0.f,0.f,0.f,0.f,0.f,0.f,0.f,0.f,0.f,0.f,0.f};
  float lp = 0.f;                                   // partial row-sum for q=l31

  int cb = 0;
#pragma unroll 1
  for (int kt = 0; kt < 32; ++kt) {
    const int nb = cb ^ 1;
    // mask word first: stays oldest in the vmcnt queue (its wait won't drain stages)
    unsigned long long mw = mrow[kt];
    if (kt + 1 < 32) {                              // prefetch next K/V tile
      gload16(Kb + (kt + 1) * 8192 + k0off, (char*)&Ks[nb][0] + i0 * 16);
      gload16(Kb + (kt + 1) * 8192 + k1off, (char*)&Ks[nb][0] + i1 * 16);
      gload16(Vb + (kt + 1) * 128 + v0off, (char*)&Vt[nb][0] + i0 * 16);
      gload16(Vb + (kt + 1) * 128 + v1off, (char*)&Vt[nb][0] + i1 * 16);
    }
#pragma unroll
    for (int kh = 0; kh < 2; ++kh) {                // 32-key blocks
      // mask bits: key = kh*32 + (reg&3)+8*(reg>>2)+4*hi -> after >>4*hi the
      // per-reg bit index is compile-time
      unsigned m32 = (unsigned)(kh ? (mw >> 32) : mw) >> (4 * hi);
      f32x16 sf = {0.f,0.f,0.f,0.f,0.f,0.f,0.f,0.f,0.f,0.f,0.f,0.f,0.f,0.f,0.f,0.f};
      __builtin_amdgcn_s_setprio(1);
#pragma unroll
      for (int c = 0; c < 4; ++c) {                 // contraction d = 64
        bf16x8 kk = ldsw(&Ks[cb][0], kh * 32 + l31, c * 16 + hi * 8);
        sf = __builtin_amdgcn_mfma_f32_32x32x16_bf16(kk, qf[c], sf, 0, 0, 0);
      }
      __builtin_amdgcn_s_setprio(0);
      // softmax: mask -> exp2 (scores pre-scaled by 0.125*log2e) -> sum -> pack bf16
      unsigned pk[8];
#pragma unroll
      for (int p = 0; p < 8; ++p) {                 // regs 2p, 2p+1 (keys ascending pair)
        const int r0 = 2 * p, r1 = 2 * p + 1;
        const int b0 = (r0 & 3) + 8 * (r0 >> 2);
        const int b1 = (r1 & 3) + 8 * (r1 >> 2);
        float s0 = sf[r0]; if (m32 & (1u << b0)) s0 = -1e30f;
        float s1 = sf[r1]; if (m32 & (1u << b1)) s1 = -1e30f;
        float e0 = __builtin_amdgcn_exp2f(s0);
        float e1 = __builtin_amdgcn_exp2f(s1);
        lp += e0 + e1;
        pk[p] = __builtin_amdgcn_perm(__builtin_bit_cast(unsigned, e1),
                                      __builtin_bit_cast(unsigned, e0), 0x07060302);
      }
      // in-register P -> PV A-frags: swap(a,b): r0 = {a.lo | b.lo_shifted_hi},
      // r1 = {a.hi_to_lo | b.hi}; gives both sub-block dword pairs directly.
      uint2v ra = __builtin_amdgcn_permlane32_swap(pk[0], pk[2], false, false);
      uint2v rb = __builtin_amdgcn_permlane32_swap(pk[1], pk[3], false, false);
      uint2v rc = __builtin_amdgcn_permlane32_swap(pk[4], pk[6], false, false);
      uint2v rd = __builtin_amdgcn_permlane32_swap(pk[5], pk[7], false, false);
      int4 ia = {(int)ra[0], (int)rb[0], (int)ra[1], (int)rb[1]};  // keys kh*32+ 0..15
      int4 ib = {(int)rc[0], (int)rd[0], (int)rc[1], (int)rd[1]};  // keys kh*32+16..31
      bf16x8 apA = __builtin_bit_cast(bf16x8, ia);
      bf16x8 apB = __builtin_bit_cast(bf16x8, ib);
      // PV: B = V^T rows (dout), contraction over this 32-key block
      __builtin_amdgcn_s_setprio(1);
      {
        bf16x8 bv;
        bv = ldsw(&Vt[cb][0], l31, kh * 32 + hi * 8);
        oacc0 = __builtin_amdgcn_mfma_f32_32x32x16_bf16(apA, bv, oacc0, 0, 0, 0);
        bv = ldsw(&Vt[cb][0], l31, kh * 32 + 16 + hi * 8);
        oacc0 = __builtin_amdgcn_mfma_f32_32x32x16_bf16(apB, bv, oacc0, 0, 0, 0);
        bv = ldsw(&Vt[cb][0], 32 + l31, kh * 32 + hi * 8);
        oacc1 = __builtin_amdgcn_mfma_f32_32x32x16_bf16(apA, bv, oacc1, 0, 0, 0);
        bv = ldsw(&Vt[cb][0], 32 + l31, kh * 32 + 16 + hi * 8);
        oacc1 = __builtin_amdgcn_mfma_f32_32x32x16_bf16(apB, bv, oacc1, 0, 0, 0);
      }
      __builtin_amdgcn_s_setprio(0);
    }
    asm volatile("s_waitcnt vmcnt(0)" ::: "memory");  // next tile staged
    __syncthreads();
    cb = nb;
  }

  // row-sum: lane l and l^32 hold the two key-halves of q=l31
  lp += __shfl_xor(lp, 32);
  float invl = 1.0f / lp;
  const int h = bh & 15;
#pragma unroll
  for (int r = 0; r < 16; ++r) {
    const int qc = (r & 3) + 8 * (r >> 2);          // oacc row -> q offset (+4*hi)
    float invr = __shfl(invl, qc + 4 * hi);         // owner lane of that q
    int qg = qt * 128 + wid * 32 + qc + 4 * hi;
    size_t base = ((size_t)b * 2048 + qg) * 1024 + h * 64 + l31;
    O[base] = f2bf(oacc0[r] * invr);
    O[base + 32] = f2bf(oacc1[r] * invr);
  }
}

extern "C" void kernel_launch(void* const* d_in, const int* in_sizes, int n_in,
                              void* d_out, int out_size, void* d_ws, size_t ws_size,
                              hipStream_t stream) {
  (void)in_sizes; (void)n_in; (void)out_size; (void)ws_size;
  const float* x = (const float*)d_in[0];
  const int* mask = (const int*)d_in[1];
  const float* Wqkv = (const float*)d_in[2];
  const float* Wout = (const float*)d_in[3];
  const float* bout = (const float*)d_in[4];
  float* out = (float*)d_out;

  unsigned short* ws = (unsigned short*)d_ws;
  unsigned short* Xb   = ws;                  // 8,388,608 elems
  unsigned short* Wq_t = Xb + 8388608;        // 3,145,728
  unsigned short* Wo_t = Wq_t + 3145728;      // 1,048,576
  unsigned short* Qa   = Wo_t + 1048576;      // 8,388,608 (pre-scaled by 0.125*log2e)
  unsigned short* Ka   = Qa + 8388608;        // 8,388,608
  unsigned short* Va   = Ka + 8388608;        // 8,388,608 (transposed [bh][64][2048])
  unsigned short* ATT  = Va + 8388608;        // 8,388,608
  unsigned long long* MP = (unsigned long long*)(ATT + 8388608);  // 2 MB

  k_cvt<<<8192, 256, 0, stream>>>(x, Xb);
  k_transpose_cvt<<<dim3(96, 32), 256, 0, stream>>>(Wqkv, Wq_t, 1024, 3072);
  k_transpose_cvt<<<dim3(32, 32), 256, 0, stream>>>(Wout, Wo_t, 1024, 1024);
  k_packmask<<<8192, 256, 0, stream>>>(mask, MP);
  k_gemm<0><<<dim3(24, 64), 256, 0, stream>>>(Xb, Wq_t, Qa, Ka, Va, nullptr, nullptr);
  k_attn<<<1024, 256, 0, stream>>>(Qa, Ka, Va, MP, ATT);
  k_gemm<1><<<dim3(8, 64), 256, 0, stream>>>(ATT, Wo_t, nullptr, nullptr, nullptr, out, bout);
}

// Round 11
// 238.550 us; speedup vs baseline: 1.0520x; 1.0520x over previous
//
#include <hip/hip_runtime.h>
#include <hip/hip_bf16.h>

// SelfAttentionMasked: B=4, N=2048, DIM=1024, H=16, DH=64
// k_prep (cvt(x) + transpose_cvt(Wqkv,Wout) + packmask, one dispatch)
// -> QKV GEMM (gload_lds+swizzle, LDS-restaged coalesced epilogue, Q pre-scaled by
// 0.125*log2e) -> flash attn (16x16 swapped QK^T, key-half pipeline, 8KB swizzled Ps,
// rolled kt loop — R9-proven 108us) -> out GEMM + bias

typedef __attribute__((ext_vector_type(8))) short bf16x8;
typedef __attribute__((ext_vector_type(4))) float f32x4;

__device__ __forceinline__ unsigned short f2bf(float f) {
  unsigned u = __builtin_bit_cast(unsigned, f);
  u += 0x7fffu + ((u >> 16) & 1u);   // RNE
  return (unsigned short)(u >> 16);
}

// async global->LDS, 16B per lane; LDS dest linear (wave-uniform base + lane*16)
__device__ __forceinline__ void gload16(const void* g, void* l) {
  __builtin_amdgcn_global_load_lds(
      (const __attribute__((address_space(1))) unsigned int*)g,
      (__attribute__((address_space(3))) unsigned int*)l, 16, 0, 0);
}

// swizzled b128 read from a [rows][64-elem] linear LDS tile staged with
// source-byte ^= ((row&7)<<4). elem must be a multiple of 8.
__device__ __forceinline__ bf16x8 ldsw(const short* base, int row, int elem) {
  const char* p = (const char*)base + row * 128 + ((elem * 2) ^ ((row & 7) << 4));
  return *(const bf16x8*)p;
}

// ---------------- fused prep: cvt(x) | transpose_cvt(Wqkv) | transpose_cvt(Wout)
// ---------------- | packmask.  All independent; branch on blockIdx range.
__global__ __launch_bounds__(256) void k_prep(
    const float* __restrict__ x, unsigned short* __restrict__ Xb,
    const float* __restrict__ Wqkv, unsigned short* __restrict__ Wq_t,
    const float* __restrict__ Wout, unsigned short* __restrict__ Wo_t,
    const int* __restrict__ mask, unsigned long long* __restrict__ MP) {
  __shared__ float tile[32][33];
  const int bid = blockIdx.x, t = threadIdx.x;
  if (bid < 8192) {
    // cvt f32 -> bf16, 1024 elems/block
    int i = (bid * 256 + t) * 4;
    float4 v = *reinterpret_cast<const float4*>(x + i);
    ushort4 o;
    o.x = f2bf(v.x); o.y = f2bf(v.y); o.z = f2bf(v.z); o.w = f2bf(v.w);
    *reinterpret_cast<ushort4*>(Xb + i) = o;
  } else if (bid < 12288) {
    // transpose + convert 32x32 tile
    const float* in; unsigned short* out; int rows, cols, bx, by;
    if (bid < 11264) { int l = bid - 8192; in = Wqkv; out = Wq_t; rows = 1024; cols = 3072; bx = l % 96; by = l / 96; }
    else             { int l = bid - 11264; in = Wout; out = Wo_t; rows = 1024; cols = 1024; bx = l & 31; by = l >> 5; }
    int tx = t & 31, ty = t >> 5;  // 32 x 8
    int c0 = bx * 32, r0 = by * 32;
#pragma unroll
    for (int i = 0; i < 32; i += 8)
      tile[ty + i][tx] = in[(size_t)(r0 + ty + i) * cols + (c0 + tx)];
    __syncthreads();
#pragma unroll
    for (int i = 0; i < 32; i += 8)
      out[(size_t)(c0 + ty + i) * rows + (r0 + tx)] = f2bf(tile[tx][ty + i]);
  } else {
    // pack mask int32 [row][2048] -> bits uint64 [row][32] (bit k = masked)
    const int row = bid - 12288;             // b*2048 + n
    const int w = t >> 6, lane = t & 63;
    const int* mrow = mask + (size_t)row * 2048;
#pragma unroll
    for (int it = 0; it < 8; ++it) {
      int key = it * 256 + w * 64 + lane;
      unsigned long long bal = __ballot(mrow[key] == 1);
      if (lane == 0) MP[(size_t)row * 32 + it * 4 + w] = bal;
    }
  }
}

// ---------------- GEMM: C[8192][N] = A[8192][1024] @ Bt[N][1024]^T ----------------
// EPI==0: LDS-restaged coalesced epilogue into Q (pre-scaled) / K [bh][2048][64],
//         V^T [bh][64][2048]. grid (24,64).  EPI==1: f32 out + bias. grid (8,64).
// Default block order (R9 showed default round-robin beats chunked XCD swizzle here).
template <int EPI>
__global__ __launch_bounds__(256) void k_gemm(
    const unsigned short* __restrict__ A, const unsigned short* __restrict__ Bt,
    unsigned short* __restrict__ Qo, unsigned short* __restrict__ Ko,
    unsigned short* __restrict__ Vo, float* __restrict__ Co,
    const float* __restrict__ bias) {
  // k-loop: As = Smem[0:8192), Bs = Smem[8192:16384). epilogue: Cs = Smem, stride 132.
  __shared__ __align__(16) short Smem[16896];   // 33792 B
  short* As = Smem;
  short* Bs = Smem + 8192;
  const int t = threadIdx.x;
  const int bn = blockIdx.x, bm = blockIdx.y;
  const int wid = t >> 6, lane = t & 63, g = lane >> 4, l15 = lane & 15;
  const int wr = wid >> 1, wc = wid & 1;
  f32x4 zero = {0.f, 0.f, 0.f, 0.f};
  f32x4 acc[4][4];
#pragma unroll
  for (int i = 0; i < 4; ++i)
#pragma unroll
    for (int j = 0; j < 4; ++j) acc[i][j] = zero;

  const char* Ab = (const char*)(A + (size_t)bm * 128 * 1024);  // row stride 2048B
  const char* Bb = (const char*)(Bt + (size_t)bn * 128 * 1024);

  for (int k0 = 0; k0 < 2048; k0 += 128) {   // K-step: 64 elems = 128 bytes
#pragma unroll
    for (int q = 0; q < 4; ++q) {
      int idx = t + q * 256, r = idx >> 3, c = idx & 7;
      int sw = (c * 16) ^ ((r & 7) << 4);
      gload16(Ab + (size_t)r * 2048 + k0 + sw, (char*)As + idx * 16);
      gload16(Bb + (size_t)r * 2048 + k0 + sw, (char*)Bs + idx * 16);
    }
    asm volatile("s_waitcnt vmcnt(0)" ::: "memory");
    __syncthreads();
#pragma unroll
    for (int ks = 0; ks < 2; ++ks) {
      bf16x8 a[4], b[4];
#pragma unroll
      for (int mi = 0; mi < 4; ++mi) a[mi] = ldsw(As, wr * 64 + mi * 16 + l15, ks * 32 + g * 8);
#pragma unroll
      for (int ni = 0; ni < 4; ++ni) b[ni] = ldsw(Bs, wc * 64 + ni * 16 + l15, ks * 32 + g * 8);
#pragma unroll
      for (int mi = 0; mi < 4; ++mi)
#pragma unroll
        for (int ni = 0; ni < 4; ++ni)
          acc[mi][ni] = __builtin_amdgcn_mfma_f32_16x16x32_bf16(a[mi], b[ni], acc[mi][ni], 0, 0, 0);
    }
    __syncthreads();   // also guards Smem reuse by the epilogue
  }

  if (EPI == 1) {
#pragma unroll
    for (int mi = 0; mi < 4; ++mi)
#pragma unroll
      for (int ni = 0; ni < 4; ++ni)
#pragma unroll
        for (int j = 0; j < 4; ++j) {
          int row = bm * 128 + wr * 64 + mi * 16 + g * 4 + j;
          int col = bn * 128 + wc * 64 + ni * 16 + l15;
          Co[(size_t)row * 1024 + col] = acc[mi][ni][j] + bias[col];
        }
    return;
  }

  // ---- EPI==0 coalesced epilogue ----
  const int s = bn >> 3;                 // 0=Q,1=K,2=V (uniform per block)
  const int h0 = (bn & 7) * 2;           // two heads in this tile
  const int bglob = (bm * 128) >> 11;    // batch (tile never straddles batches)
  const int n0 = (bm * 128) & 2047;

  if (s < 2) {
    const float qs = (s == 0) ? 0.18033688011112042f : 1.0f;  // 0.125*log2(e) for Q
    // stage Cs[row][col], stride 132 shorts
#pragma unroll
    for (int mi = 0; mi < 4; ++mi)
#pragma unroll
      for (int ni = 0; ni < 4; ++ni)
#pragma unroll
        for (int j = 0; j < 4; ++j)
          Smem[(wr * 64 + mi * 16 + g * 4 + j) * 132 + wc * 64 + ni * 16 + l15] =
              (short)f2bf(acc[mi][ni][j] * qs);
    __syncthreads();
    // copy out: thread -> row r, head-half hh; 64 shorts = 128B contiguous dest
    int r = t >> 1, hh = t & 1;
    unsigned short* dst = (s == 0 ? Qo : Ko) +
        (((size_t)(bglob * 16 + h0 + hh)) * 2048 + n0 + r) * 64;
    const short* src = Smem + r * 132 + hh * 64;
#pragma unroll
    for (int k = 0; k < 8; ++k) {
      uint2 a = *reinterpret_cast<const uint2*>(src + k * 8);
      uint2 b2 = *reinterpret_cast<const uint2*>(src + k * 8 + 4);
      uint4 w = {a.x, a.y, b2.x, b2.y};
      *reinterpret_cast<uint4*>(dst + k * 8) = w;
    }
  } else {
    // V: stage TRANSPOSED Cs_t[col][row] stride 132; per-fragment 4 j-rows adjacent -> b64
#pragma unroll
    for (int mi = 0; mi < 4; ++mi)
#pragma unroll
      for (int ni = 0; ni < 4; ++ni) {
        unsigned x0 = f2bf(acc[mi][ni][0]), x1 = f2bf(acc[mi][ni][1]);
        unsigned x2 = f2bf(acc[mi][ni][2]), x3 = f2bf(acc[mi][ni][3]);
        uint2 pk = {x0 | (x1 << 16), x2 | (x3 << 16)};
        int col = wc * 64 + ni * 16 + l15;
        int row = wr * 64 + mi * 16 + g * 4;
        *reinterpret_cast<uint2*>(Smem + col * 132 + row) = pk;
      }
    __syncthreads();
    // copy out: thread -> col c (head h, dim d), row-half seg; 64 shorts contiguous dest
    int c = t >> 1, seg = t & 1;
    int h = h0 + (c >> 6), d = c & 63;
    unsigned short* dst = Vo + ((size_t)(bglob * 16 + h) * 64 + d) * 2048 + n0 + seg * 64;
    const short* src = Smem + c * 132 + seg * 64;
#pragma unroll
    for (int k = 0; k < 8; ++k) {
      uint2 a = *reinterpret_cast<const uint2*>(src + k * 8);
      uint2 b2 = *reinterpret_cast<const uint2*>(src + k * 8 + 4);
      uint4 w = {a.x, a.y, b2.x, b2.y};
      *reinterpret_cast<uint4*>(dst + k * 8) = w;
    }
  }
}

// ---------------- flash attention (R9-proven) ----------------
// grid 1024 (XCD-swizzled), 512 threads = 8 waves; QBLK=128, KV tile 64, dbuf.
// Swapped QK^T: S^T = mfma(K, Q) -> lane (g,l15) holds 16 keys for q=l15.
// Key-half pipeline: {QK(2 frags) -> softmax -> pack -> PV} per 32-key half,
// one 8KB swizzled Ps. LDS = 40960B -> 4 blocks/CU at <=64 VGPR. Loop ROLLED with
// runtime cb (32-VGPR codegen). Rejected by measurement: ones-MFMA row-sum (R8,
// +15us dep chain), 32x32+permlane in-reg P (R10, +10us: half the waves).
__global__ __launch_bounds__(512, 8) void k_attn(
    const unsigned short* __restrict__ Q, const unsigned short* __restrict__ K,
    const unsigned short* __restrict__ Vt_g, const unsigned long long* __restrict__ pack,
    unsigned short* __restrict__ O) {
  __shared__ __align__(16) short Ks[2][64 * 64];    // 16KB
  __shared__ __align__(16) short Vt[2][64 * 64];    // 16KB  [d][key]
  __shared__ __align__(16) short Ps[8][16 * 32];    // 8KB per-wave P half [q][32key], swz
  const int bid0 = blockIdx.x;
  const int bid = (bid0 & 7) * 128 + (bid0 >> 3);   // XCD chunked swizzle (1024%8==0)
  const int qt = bid & 15, bh = bid >> 4;           // 16 q-tiles of 128
  const int b = bh >> 4;
  const int t = threadIdx.x, wid = t >> 6, lane = t & 63, g = lane >> 4, l15 = lane & 15;
  const char* Kb = (const char*)(K + (size_t)bh * (2048 * 64));     // row 128B
  const char* Vb = (const char*)(Vt_g + (size_t)bh * (64 * 2048));  // row 4096B
  const unsigned short* Qb = Q + (size_t)bh * (2048 * 64);

  // per-lane loop-invariant offsets
  const int sr = t >> 3, sc = t & 7;
  const int sw_src = (sc * 16) ^ ((sr & 7) << 4);
  char* PwB = (char*)&Ps[wid][0];                   // 16 rows x 64B
  const int ps_rd  = (l15 * 64 + g * 16) ^ ((l15 & 7) << 4);  // b128 read
  const int ps_wr0 = (l15 * 64 + g * 8) ^ ((l15 & 7) << 4);   // b64 write nf2=0
  // nf2=1 write offset == ps_wr0 ^ 32 (bit 5 untouched by +g*8, l15*64)

  // prologue: stage K/V tile 0
  gload16(Kb + (size_t)sr * 128 + sw_src, (char*)&Ks[0][0] + t * 16);
  gload16(Vb + (size_t)sr * 4096 + sw_src, (char*)&Vt[0][0] + t * 16);
  // Q fragments to registers (B-operand of swapped QK^T): q = l15 row of wave's block
  const int qrow = qt * 128 + wid * 16 + l15;
  bf16x8 qf0 = *reinterpret_cast<const bf16x8*>(Qb + (size_t)qrow * 64 + g * 8);
  bf16x8 qf1 = *reinterpret_cast<const bf16x8*>(Qb + (size_t)qrow * 64 + 32 + g * 8);
  const unsigned long long* mrow = pack + ((size_t)b * 2048 + qrow) * 32;
  asm volatile("s_waitcnt vmcnt(0)" ::: "memory");
  __syncthreads();

  f32x4 zero = {0.f, 0.f, 0.f, 0.f};
  f32x4 oacc[4];
#pragma unroll
  for (int nf = 0; nf < 4; ++nf) oacc[nf] = zero;
  float lp = 0.f;                                   // partial row-sum for q=l15

  int cb = 0;
#pragma unroll 1
  for (int kt = 0; kt < 32; ++kt) {
    const int nb = cb ^ 1;
    // mask word first: stays oldest in the vmcnt queue (its wait won't drain stages)
    unsigned long long mw = mrow[kt];
    if (kt + 1 < 32) {                              // prefetch next K/V tile
      gload16(Kb + (size_t)((kt + 1) * 64 + sr) * 128 + sw_src, (char*)&Ks[nb][0] + t * 16);
      gload16(Vb + (size_t)sr * 4096 + (kt + 1) * 128 + sw_src, (char*)&Vt[nb][0] + t * 16);
    }
    unsigned mlo = (unsigned)mw >> (g * 4);         // key nf*16+g*4+j -> bit nf*16+j
    unsigned mhi = (unsigned)(mw >> 32) >> (g * 4);
#pragma unroll
    for (int kh = 0; kh < 2; ++kh) {                // 32-key half pipeline
      f32x4 sf[2] = {zero, zero};
      __builtin_amdgcn_s_setprio(1);
#pragma unroll
      for (int ds = 0; ds < 2; ++ds) {              // d-halves (contraction)
        bf16x8 qk = ds ? qf1 : qf0;
#pragma unroll
        for (int nf2 = 0; nf2 < 2; ++nf2) {
          bf16x8 kk = ldsw(&Ks[cb][0], (kh * 2 + nf2) * 16 + l15, ds * 32 + g * 8);
          sf[nf2] = __builtin_amdgcn_mfma_f32_16x16x32_bf16(kk, qk, sf[nf2], 0, 0, 0);
        }
      }
      __builtin_amdgcn_s_setprio(0);
      // softmax half: mask bits, exp2 (scores pre-scaled by 0.125*log2e), pack
      unsigned msrc = kh ? mhi : mlo;
#pragma unroll
      for (int nf2 = 0; nf2 < 2; ++nf2) {
        unsigned eu[4];
#pragma unroll
        for (int j = 0; j < 4; ++j) {
          float s = sf[nf2][j];
          if (msrc & (1u << (nf2 * 16 + j))) s = -1e30f;
          float e = __builtin_amdgcn_exp2f(s);
          lp += e;
          eu[j] = __builtin_bit_cast(unsigned, e);
        }
        uint2 pk;                                    // trunc-bf16 pack (P>=0)
        pk.x = __builtin_amdgcn_perm(eu[1], eu[0], 0x07060302);
        pk.y = __builtin_amdgcn_perm(eu[3], eu[2], 0x07060302);
        *reinterpret_cast<uint2*>(PwB + (nf2 ? (ps_wr0 ^ 32) : ps_wr0)) = pk;
      }
      asm volatile("s_waitcnt lgkmcnt(0)" ::: "memory");
      __builtin_amdgcn_sched_barrier(0);
      // PV half: A = P[q][32 keys], B = Vt rows (d), k-dim = this key half
      bf16x8 ap = *reinterpret_cast<const bf16x8*>(PwB + ps_rd);
      __builtin_amdgcn_s_setprio(1);
#pragma unroll
      for (int nf = 0; nf < 4; ++nf) {
        bf16x8 bv = ldsw(&Vt[cb][0], nf * 16 + l15, kh * 32 + g * 8);
        oacc[nf] = __builtin_amdgcn_mfma_f32_16x16x32_bf16(ap, bv, oacc[nf], 0, 0, 0);
      }
      __builtin_amdgcn_s_setprio(0);
    }
    asm volatile("s_waitcnt vmcnt(0)" ::: "memory");  // next tile staged
    __syncthreads();
    cb = nb;
  }

  // total row-sum for q=l15 (4 lanes per q across g-groups), redistribute inverse
  float l = lp;
  l += __shfl_xor(l, 16);
  l += __shfl_xor(l, 32);
  float invl = 1.0f / l;
  float inv[4];
#pragma unroll
  for (int j = 0; j < 4; ++j) inv[j] = __shfl(invl, g * 4 + j);  // lane l15==g*4+j

  // write attention output: ATT[b][n][h*64+d] bf16 ; O-tile: q=g*4+j, d=nf*16+l15
  const int h = bh & 15;
#pragma unroll
  for (int nf = 0; nf < 4; ++nf) {
#pragma unroll
    for (int j = 0; j < 4; ++j) {
      int qg = qt * 128 + wid * 16 + g * 4 + j;
      int d = nf * 16 + l15;
      O[((size_t)b * 2048 + qg) * 1024 + h * 64 + d] = f2bf(oacc[nf][j] * inv[j]);
    }
  }
}

extern "C" void kernel_launch(void* const* d_in, const int* in_sizes, int n_in,
                              void* d_out, int out_size, void* d_ws, size_t ws_size,
                              hipStream_t stream) {
  (void)in_sizes; (void)n_in; (void)out_size; (void)ws_size;
  const float* x = (const float*)d_in[0];
  const int* mask = (const int*)d_in[1];
  const float* Wqkv = (const float*)d_in[2];
  const float* Wout = (const float*)d_in[3];
  const float* bout = (const float*)d_in[4];
  float* out = (float*)d_out;

  unsigned short* ws = (unsigned short*)d_ws;
  unsigned short* Xb   = ws;                  // 8,388,608 elems
  unsigned short* Wq_t = Xb + 8388608;        // 3,145,728
  unsigned short* Wo_t = Wq_t + 3145728;      // 1,048,576
  unsigned short* Qa   = Wo_t + 1048576;      // 8,388,608 (pre-scaled by 0.125*log2e)
  unsigned short* Ka   = Qa + 8388608;        // 8,388,608
  unsigned short* Va   = Ka + 8388608;        // 8,388,608 (transposed [bh][64][2048])
  unsigned short* ATT  = Va + 8388608;        // 8,388,608
  unsigned long long* MP = (unsigned long long*)(ATT + 8388608);  // 2 MB

  k_prep<<<20480, 256, 0, stream>>>(x, Xb, Wqkv, Wq_t, Wout, Wo_t, mask, MP);
  k_gemm<0><<<dim3(24, 64), 256, 0, stream>>>(Xb, Wq_t, Qa, Ka, Va, nullptr, nullptr);
  k_attn<<<1024, 512, 0, stream>>>(Qa, Ka, Va, MP, ATT);
  k_gemm<1><<<dim3(8, 64), 256, 0, stream>>>(ATT, Wo_t, nullptr, nullptr, nullptr, out, bout);
}

// Round 12
// 237.927 us; speedup vs baseline: 1.0548x; 1.0026x over previous
//
#include <hip/hip_runtime.h>
#include <hip/hip_bf16.h>

// SelfAttentionMasked: B=4, N=2048, DIM=1024, H=16, DH=64
// k_prep (cvt(x) + transpose_cvt(Wqkv,Wout) + packmask, one dispatch)
// -> QKV GEMM (gload_lds+swizzle, LDS-restaged coalesced epilogue, Q pre-scaled by
// 0.125*log2e) -> flash attn (16x16 swapped QK^T, key-half pipeline, single-buffered
// V + counted mid-tile join, 32KB LDS -> 4 blocks/CU) -> out GEMM + bias

typedef __attribute__((ext_vector_type(8))) short bf16x8;
typedef __attribute__((ext_vector_type(4))) float f32x4;

__device__ __forceinline__ unsigned short f2bf(float f) {
  unsigned u = __builtin_bit_cast(unsigned, f);
  u += 0x7fffu + ((u >> 16) & 1u);   // RNE
  return (unsigned short)(u >> 16);
}

// async global->LDS, 16B per lane; LDS dest linear (wave-uniform base + lane*16)
__device__ __forceinline__ void gload16(const void* g, void* l) {
  __builtin_amdgcn_global_load_lds(
      (const __attribute__((address_space(1))) unsigned int*)g,
      (__attribute__((address_space(3))) unsigned int*)l, 16, 0, 0);
}

// swizzled b128 read from a [rows][64-elem] linear LDS tile staged with
// source-byte ^= ((row&7)<<4). elem must be a multiple of 8.
__device__ __forceinline__ bf16x8 ldsw(const short* base, int row, int elem) {
  const char* p = (const char*)base + row * 128 + ((elem * 2) ^ ((row & 7) << 4));
  return *(const bf16x8*)p;
}

// ---------------- fused prep: cvt(x) | transpose_cvt(Wqkv) | transpose_cvt(Wout)
// ---------------- | packmask.  All independent; branch on blockIdx range.
__global__ __launch_bounds__(256) void k_prep(
    const float* __restrict__ x, unsigned short* __restrict__ Xb,
    const float* __restrict__ Wqkv, unsigned short* __restrict__ Wq_t,
    const float* __restrict__ Wout, unsigned short* __restrict__ Wo_t,
    const int* __restrict__ mask, unsigned long long* __restrict__ MP) {
  __shared__ float tile[32][33];
  const int bid = blockIdx.x, t = threadIdx.x;
  if (bid < 8192) {
    // cvt f32 -> bf16, 1024 elems/block
    int i = (bid * 256 + t) * 4;
    float4 v = *reinterpret_cast<const float4*>(x + i);
    ushort4 o;
    o.x = f2bf(v.x); o.y = f2bf(v.y); o.z = f2bf(v.z); o.w = f2bf(v.w);
    *reinterpret_cast<ushort4*>(Xb + i) = o;
  } else if (bid < 12288) {
    // transpose + convert 32x32 tile
    const float* in; unsigned short* out; int rows, cols, bx, by;
    if (bid < 11264) { int l = bid - 8192; in = Wqkv; out = Wq_t; rows = 1024; cols = 3072; bx = l % 96; by = l / 96; }
    else             { int l = bid - 11264; in = Wout; out = Wo_t; rows = 1024; cols = 1024; bx = l & 31; by = l >> 5; }
    int tx = t & 31, ty = t >> 5;  // 32 x 8
    int c0 = bx * 32, r0 = by * 32;
#pragma unroll
    for (int i = 0; i < 32; i += 8)
      tile[ty + i][tx] = in[(size_t)(r0 + ty + i) * cols + (c0 + tx)];
    __syncthreads();
#pragma unroll
    for (int i = 0; i < 32; i += 8)
      out[(size_t)(c0 + ty + i) * rows + (r0 + tx)] = f2bf(tile[tx][ty + i]);
  } else {
    // pack mask int32 [row][2048] -> bits uint64 [row][32] (bit k = masked)
    const int row = bid - 12288;             // b*2048 + n
    const int w = t >> 6, lane = t & 63;
    const int* mrow = mask + (size_t)row * 2048;
#pragma unroll
    for (int it = 0; it < 8; ++it) {
      int key = it * 256 + w * 64 + lane;
      unsigned long long bal = __ballot(mrow[key] == 1);
      if (lane == 0) MP[(size_t)row * 32 + it * 4 + w] = bal;
    }
  }
}

// ---------------- GEMM: C[8192][N] = A[8192][1024] @ Bt[N][1024]^T ----------------
// EPI==0: LDS-restaged coalesced epilogue into Q (pre-scaled) / K [bh][2048][64],
//         V^T [bh][64][2048]. grid (24,64).  EPI==1: f32 out + bias. grid (8,64).
// Default block order (R9 showed default round-robin beats chunked XCD swizzle here).
template <int EPI>
__global__ __launch_bounds__(256) void k_gemm(
    const unsigned short* __restrict__ A, const unsigned short* __restrict__ Bt,
    unsigned short* __restrict__ Qo, unsigned short* __restrict__ Ko,
    unsigned short* __restrict__ Vo, float* __restrict__ Co,
    const float* __restrict__ bias) {
  // k-loop: As = Smem[0:8192), Bs = Smem[8192:16384). epilogue: Cs = Smem, stride 132.
  __shared__ __align__(16) short Smem[16896];   // 33792 B
  short* As = Smem;
  short* Bs = Smem + 8192;
  const int t = threadIdx.x;
  const int bn = blockIdx.x, bm = blockIdx.y;
  const int wid = t >> 6, lane = t & 63, g = lane >> 4, l15 = lane & 15;
  const int wr = wid >> 1, wc = wid & 1;
  f32x4 zero = {0.f, 0.f, 0.f, 0.f};
  f32x4 acc[4][4];
#pragma unroll
  for (int i = 0; i < 4; ++i)
#pragma unroll
    for (int j = 0; j < 4; ++j) acc[i][j] = zero;

  const char* Ab = (const char*)(A + (size_t)bm * 128 * 1024);  // row stride 2048B
  const char* Bb = (const char*)(Bt + (size_t)bn * 128 * 1024);

  for (int k0 = 0; k0 < 2048; k0 += 128) {   // K-step: 64 elems = 128 bytes
#pragma unroll
    for (int q = 0; q < 4; ++q) {
      int idx = t + q * 256, r = idx >> 3, c = idx & 7;
      int sw = (c * 16) ^ ((r & 7) << 4);
      gload16(Ab + (size_t)r * 2048 + k0 + sw, (char*)As + idx * 16);
      gload16(Bb + (size_t)r * 2048 + k0 + sw, (char*)Bs + idx * 16);
    }
    asm volatile("s_waitcnt vmcnt(0)" ::: "memory");
    __syncthreads();
#pragma unroll
    for (int ks = 0; ks < 2; ++ks) {
      bf16x8 a[4], b[4];
#pragma unroll
      for (int mi = 0; mi < 4; ++mi) a[mi] = ldsw(As, wr * 64 + mi * 16 + l15, ks * 32 + g * 8);
#pragma unroll
      for (int ni = 0; ni < 4; ++ni) b[ni] = ldsw(Bs, wc * 64 + ni * 16 + l15, ks * 32 + g * 8);
#pragma unroll
      for (int mi = 0; mi < 4; ++mi)
#pragma unroll
        for (int ni = 0; ni < 4; ++ni)
          acc[mi][ni] = __builtin_amdgcn_mfma_f32_16x16x32_bf16(a[mi], b[ni], acc[mi][ni], 0, 0, 0);
    }
    __syncthreads();   // also guards Smem reuse by the epilogue
  }

  if (EPI == 1) {
#pragma unroll
    for (int mi = 0; mi < 4; ++mi)
#pragma unroll
      for (int ni = 0; ni < 4; ++ni)
#pragma unroll
        for (int j = 0; j < 4; ++j) {
          int row = bm * 128 + wr * 64 + mi * 16 + g * 4 + j;
          int col = bn * 128 + wc * 64 + ni * 16 + l15;
          Co[(size_t)row * 1024 + col] = acc[mi][ni][j] + bias[col];
        }
    return;
  }

  // ---- EPI==0 coalesced epilogue ----
  const int s = bn >> 3;                 // 0=Q,1=K,2=V (uniform per block)
  const int h0 = (bn & 7) * 2;           // two heads in this tile
  const int bglob = (bm * 128) >> 11;    // batch (tile never straddles batches)
  const int n0 = (bm * 128) & 2047;

  if (s < 2) {
    const float qs = (s == 0) ? 0.18033688011112042f : 1.0f;  // 0.125*log2(e) for Q
    // stage Cs[row][col], stride 132 shorts
#pragma unroll
    for (int mi = 0; mi < 4; ++mi)
#pragma unroll
      for (int ni = 0; ni < 4; ++ni)
#pragma unroll
        for (int j = 0; j < 4; ++j)
          Smem[(wr * 64 + mi * 16 + g * 4 + j) * 132 + wc * 64 + ni * 16 + l15] =
              (short)f2bf(acc[mi][ni][j] * qs);
    __syncthreads();
    // copy out: thread -> row r, head-half hh; 64 shorts = 128B contiguous dest
    int r = t >> 1, hh = t & 1;
    unsigned short* dst = (s == 0 ? Qo : Ko) +
        (((size_t)(bglob * 16 + h0 + hh)) * 2048 + n0 + r) * 64;
    const short* src = Smem + r * 132 + hh * 64;
#pragma unroll
    for (int k = 0; k < 8; ++k) {
      uint2 a = *reinterpret_cast<const uint2*>(src + k * 8);
      uint2 b2 = *reinterpret_cast<const uint2*>(src + k * 8 + 4);
      uint4 w = {a.x, a.y, b2.x, b2.y};
      *reinterpret_cast<uint4*>(dst + k * 8) = w;
    }
  } else {
    // V: stage TRANSPOSED Cs_t[col][row] stride 132; per-fragment 4 j-rows adjacent -> b64
#pragma unroll
    for (int mi = 0; mi < 4; ++mi)
#pragma unroll
      for (int ni = 0; ni < 4; ++ni) {
        unsigned x0 = f2bf(acc[mi][ni][0]), x1 = f2bf(acc[mi][ni][1]);
        unsigned x2 = f2bf(acc[mi][ni][2]), x3 = f2bf(acc[mi][ni][3]);
        uint2 pk = {x0 | (x1 << 16), x2 | (x3 << 16)};
        int col = wc * 64 + ni * 16 + l15;
        int row = wr * 64 + mi * 16 + g * 4;
        *reinterpret_cast<uint2*>(Smem + col * 132 + row) = pk;
      }
    __syncthreads();
    // copy out: thread -> col c (head h, dim d), row-half seg; 64 shorts contiguous dest
    int c = t >> 1, seg = t & 1;
    int h = h0 + (c >> 6), d = c & 63;
    unsigned short* dst = Vo + ((size_t)(bglob * 16 + h) * 64 + d) * 2048 + n0 + seg * 64;
    const short* src = Smem + c * 132 + seg * 64;
#pragma unroll
    for (int k = 0; k < 8; ++k) {
      uint2 a = *reinterpret_cast<const uint2*>(src + k * 8);
      uint2 b2 = *reinterpret_cast<const uint2*>(src + k * 8 + 4);
      uint4 w = {a.x, a.y, b2.x, b2.y};
      *reinterpret_cast<uint4*>(dst + k * 8) = w;
    }
  }
}

// ---------------- flash attention ----------------
// grid 1024 (XCD-swizzled), 512 threads = 8 waves; QBLK=128, KV tile 64.
// Swapped QK^T: S^T = mfma(K, Q) -> lane (g,l15) holds 16 keys for q=l15.
// Key-half pipeline: {QK(2 frags) -> softmax -> pack -> PV} per 32-key half.
// K double-buffered; V SINGLE-buffered (staged at tile top, joined mid-tile with
// counted vmcnt + RAW s_barrier -- __syncthreads would drain vmcnt(0) and kill the
// K prefetch overlap). LDS = 32768B -> 4 blocks/CU (32 waves, single grid phase;
// the 40KB dbuf-V variant only fit 3 -> 66% occupancy two-phase tail).
__global__ __launch_bounds__(512, 8) void k_attn(
    const unsigned short* __restrict__ Q, const unsigned short* __restrict__ K,
    const unsigned short* __restrict__ Vt_g, const unsigned long long* __restrict__ pack,
    unsigned short* __restrict__ O) {
  __shared__ __align__(16) short Ks[2][64 * 64];    // 16KB
  __shared__ __align__(16) short Vt[64 * 64];       // 8KB  [d][key], single buffer
  __shared__ __align__(16) short Ps[8][16 * 32];    // 8KB per-wave P half [q][32key], swz
  const int bid0 = blockIdx.x;
  const int bid = (bid0 & 7) * 128 + (bid0 >> 3);   // XCD chunked swizzle (1024%8==0)
  const int qt = bid & 15, bh = bid >> 4;           // 16 q-tiles of 128
  const int b = bh >> 4;
  const int t = threadIdx.x, wid = t >> 6, lane = t & 63, g = lane >> 4, l15 = lane & 15;
  const char* Kb = (const char*)(K + (size_t)bh * (2048 * 64));     // row 128B
  const char* Vb = (const char*)(Vt_g + (size_t)bh * (64 * 2048));  // row 4096B
  const unsigned short* Qb = Q + (size_t)bh * (2048 * 64);

  // per-lane loop-invariant offsets
  const int sr = t >> 3, sc = t & 7;
  const int sw_src = (sc * 16) ^ ((sr & 7) << 4);
  char* PwB = (char*)&Ps[wid][0];                   // 16 rows x 64B
  const int ps_rd  = (l15 * 64 + g * 16) ^ ((l15 & 7) << 4);  // b128 read
  const int ps_wr0 = (l15 * 64 + g * 8) ^ ((l15 & 7) << 4);   // b64 write nf2=0
  // nf2=1 write offset == ps_wr0 ^ 32 (bit 5 untouched by +g*8, l15*64)

  // prologue: stage K tile 0 only (V(0) staged inside tile 0)
  gload16(Kb + (size_t)sr * 128 + sw_src, (char*)&Ks[0][0] + t * 16);
  // Q fragments to registers (B-operand of swapped QK^T): q = l15 row of wave's block
  const int qrow = qt * 128 + wid * 16 + l15;
  bf16x8 qf0 = *reinterpret_cast<const bf16x8*>(Qb + (size_t)qrow * 64 + g * 8);
  bf16x8 qf1 = *reinterpret_cast<const bf16x8*>(Qb + (size_t)qrow * 64 + 32 + g * 8);
  const unsigned long long* mrow = pack + ((size_t)b * 2048 + qrow) * 32;
  asm volatile("s_waitcnt vmcnt(0)" ::: "memory");
  __syncthreads();

  f32x4 zero = {0.f, 0.f, 0.f, 0.f};
  f32x4 oacc[4];
#pragma unroll
  for (int nf = 0; nf < 4; ++nf) oacc[nf] = zero;
  float lp = 0.f;                                   // partial row-sum for q=l15

  int cb = 0;
#pragma unroll 1
  for (int kt = 0; kt < 32; ++kt) {
    const int nb = cb ^ 1;
    // issue order matters for counted vmcnt: mask (oldest), V(t), K(t+1) (newest)
    unsigned long long mw = mrow[kt];
    gload16(Vb + (size_t)sr * 4096 + kt * 128 + sw_src, (char*)&Vt[0] + t * 16);
    if (kt + 1 < 32)
      gload16(Kb + (size_t)((kt + 1) * 64 + sr) * 128 + sw_src, (char*)&Ks[nb][0] + t * 16);
    unsigned mlo = (unsigned)mw >> (g * 4);         // key nf*16+g*4+j -> bit nf*16+j
    unsigned mhi = (unsigned)(mw >> 32) >> (g * 4);
#pragma unroll
    for (int kh = 0; kh < 2; ++kh) {                // 32-key half pipeline
      f32x4 sf[2] = {zero, zero};
      __builtin_amdgcn_s_setprio(1);
#pragma unroll
      for (int ds = 0; ds < 2; ++ds) {              // d-halves (contraction)
        bf16x8 qk = ds ? qf1 : qf0;
#pragma unroll
        for (int nf2 = 0; nf2 < 2; ++nf2) {
          bf16x8 kk = ldsw(&Ks[cb][0], (kh * 2 + nf2) * 16 + l15, ds * 32 + g * 8);
          sf[nf2] = __builtin_amdgcn_mfma_f32_16x16x32_bf16(kk, qk, sf[nf2], 0, 0, 0);
        }
      }
      __builtin_amdgcn_s_setprio(0);
      // softmax half: mask bits, exp2 (scores pre-scaled by 0.125*log2e), pack
      unsigned msrc = kh ? mhi : mlo;
#pragma unroll
      for (int nf2 = 0; nf2 < 2; ++nf2) {
        unsigned eu[4];
#pragma unroll
        for (int j = 0; j < 4; ++j) {
          float s = sf[nf2][j];
          if (msrc & (1u << (nf2 * 16 + j))) s = -1e30f;
          float e = __builtin_amdgcn_exp2f(s);
          lp += e;
          eu[j] = __builtin_bit_cast(unsigned, e);
        }
        uint2 pk;                                    // trunc-bf16 pack (P>=0)
        pk.x = __builtin_amdgcn_perm(eu[1], eu[0], 0x07060302);
        pk.y = __builtin_amdgcn_perm(eu[3], eu[2], 0x07060302);
        *reinterpret_cast<uint2*>(PwB + (nf2 ? (ps_wr0 ^ 32) : ps_wr0)) = pk;
      }
      if (kh == 0) {
        // mid-tile join: V(t) staged for all waves (K(t+1) stays in flight), Ps drained
        if (kt + 1 < 32) asm volatile("s_waitcnt vmcnt(1) lgkmcnt(0)" ::: "memory");
        else             asm volatile("s_waitcnt vmcnt(0) lgkmcnt(0)" ::: "memory");
        __builtin_amdgcn_s_barrier();
        __builtin_amdgcn_sched_barrier(0);
      } else {
        // within-wave Ps write->read ordering only
        asm volatile("s_waitcnt lgkmcnt(0)" ::: "memory");
        __builtin_amdgcn_sched_barrier(0);
      }
      // PV half: A = P[q][32 keys], B = Vt rows (d), k-dim = this key half
      bf16x8 ap = *reinterpret_cast<const bf16x8*>(PwB + ps_rd);
      __builtin_amdgcn_s_setprio(1);
#pragma unroll
      for (int nf = 0; nf < 4; ++nf) {
        bf16x8 bv = ldsw(&Vt[0], nf * 16 + l15, kh * 32 + g * 8);
        oacc[nf] = __builtin_amdgcn_mfma_f32_16x16x32_bf16(ap, bv, oacc[nf], 0, 0, 0);
      }
      __builtin_amdgcn_s_setprio(0);
    }
    // end-of-tile: K(t+1) staged (only outstanding load); also fences Vt reuse
    asm volatile("s_waitcnt vmcnt(0)" ::: "memory");
    __builtin_amdgcn_s_barrier();
    cb = nb;
  }

  // total row-sum for q=l15 (4 lanes per q across g-groups), redistribute inverse
  float l = lp;
  l += __shfl_xor(l, 16);
  l += __shfl_xor(l, 32);
  float invl = 1.0f / l;
  float inv[4];
#pragma unroll
  for (int j = 0; j < 4; ++j) inv[j] = __shfl(invl, g * 4 + j);  // lane l15==g*4+j

  // write attention output: ATT[b][n][h*64+d] bf16 ; O-tile: q=g*4+j, d=nf*16+l15
  const int h = bh & 15;
#pragma unroll
  for (int nf = 0; nf < 4; ++nf) {
#pragma unroll
    for (int j = 0; j < 4; ++j) {
      int qg = qt * 128 + wid * 16 + g * 4 + j;
      int d = nf * 16 + l15;
      O[((size_t)b * 2048 + qg) * 1024 + h * 64 + d] = f2bf(oacc[nf][j] * inv[j]);
    }
  }
}

extern "C" void kernel_launch(void* const* d_in, const int* in_sizes, int n_in,
                              void* d_out, int out_size, void* d_ws, size_t ws_size,
                              hipStream_t stream) {
  (void)in_sizes; (void)n_in; (void)out_size; (void)ws_size;
  const float* x = (const float*)d_in[0];
  const int* mask = (const int*)d_in[1];
  const float* Wqkv = (const float*)d_in[2];
  const float* Wout = (const float*)d_in[3];
  const float* bout = (const float*)d_in[4];
  float* out = (float*)d_out;

  unsigned short* ws = (unsigned short*)d_ws;
  unsigned short* Xb   = ws;                  // 8,388,608 elems
  unsigned short* Wq_t = Xb + 8388608;        // 3,145,728
  unsigned short* Wo_t = Wq_t + 3145728;      // 1,048,576
  unsigned short* Qa   = Wo_t + 1048576;      // 8,388,608 (pre-scaled by 0.125*log2e)
  unsigned short* Ka   = Qa + 8388608;        // 8,388,608
  unsigned short* Va   = Ka + 8388608;        // 8,388,608 (transposed [bh][64][2048])
  unsigned short* ATT  = Va + 8388608;        // 8,388,608
  unsigned long long* MP = (unsigned long long*)(ATT + 8388608);  // 2 MB

  k_prep<<<20480, 256, 0, stream>>>(x, Xb, Wqkv, Wq_t, Wout, Wo_t, mask, MP);
  k_gemm<0><<<dim3(24, 64), 256, 0, stream>>>(Xb, Wq_t, Qa, Ka, Va, nullptr, nullptr);
  k_attn<<<1024, 512, 0, stream>>>(Qa, Ka, Va, MP, ATT);
  k_gemm<1><<<dim3(8, 64), 256, 0, stream>>>(ATT, Wo_t, nullptr, nullptr, nullptr, out, bout);
}